// Round 4
// baseline (312.860 us; speedup 1.0000x reference)
//
#include <hip/hip_runtime.h>

#define N_ROWS 16384
#define DDIM   256
#define VCODES 8192
#define BETA   0.25f

using f16   = _Float16;
using f16x4 = __attribute__((ext_vector_type(4))) _Float16;
using f16x8 = __attribute__((ext_vector_type(8))) _Float16;
using f32x4 = __attribute__((ext_vector_type(4))) float;

typedef __attribute__((address_space(1))) const unsigned int gu32_t;
typedef __attribute__((address_space(3))) unsigned int       lu32_t;

__device__ __forceinline__ void gload16(const void* g, void* l) {
    __builtin_amdgcn_global_load_lds((gu32_t*)g, (lu32_t*)l, 16, 0, 0);
}

// ============================================================================
// Packed fragment-major layout (validated in R3 call-1):
//   array[row_tile][k_tile][512 f16]  (1 KB per 16-row x 32-col subtile)
//   element (r, c) of a subtile at f16 index (c>>3)*128 + r*8 + (c&7)
//   == exactly lane*8+j order for the mfma_f32_16x16x32_f16 A/B fragment.
//   k_tiles 0..7  = hi half (cols 0..255); 8..15 = lo residual half.
// ============================================================================

__global__ void split_lat(const float* __restrict__ lat, f16* __restrict__ Ap) {
    int t = blockIdx.x * 256 + threadIdx.x;
    float4 x = *(const float4*)&lat[(size_t)t * 4];
    int row = t >> 6;
    int c   = (t & 63) * 4;
    f16 h0 = (f16)x.x, h1 = (f16)x.y, h2 = (f16)x.z, h3 = (f16)x.w;
    f16 l0 = (f16)(x.x - (float)h0), l1 = (f16)(x.y - (float)h1);
    f16 l2 = (f16)(x.z - (float)h2), l3 = (f16)(x.w - (float)h3);
    f16x4 hi = {h0, h1, h2, h3}, lo = {l0, l1, l2, l3};
    int kt  = c >> 5;
    int sub = ((c & 31) >> 3) * 128 + (row & 15) * 8 + (c & 7);
    size_t base = ((size_t)(row >> 4) * 16);
    *(f16x4*)&Ap[(base + kt)     * 512 + sub] = hi;
    *(f16x4*)&Ap[(base + kt + 8) * 512 + sub] = lo;
}

__global__ void split_cb(const float* __restrict__ cb, f16* __restrict__ Bp) {
    int t = blockIdx.x * 256 + threadIdx.x;
    float4 e = *(const float4*)&cb[(size_t)t * 4];
    float ex = e.x * 64.0f, ey = e.y * 64.0f, ez = e.z * 64.0f, ew = e.w * 64.0f;
    int row = t >> 6;
    int c   = (t & 63) * 4;
    f16 h0 = (f16)ex, h1 = (f16)ey, h2 = (f16)ez, h3 = (f16)ew;
    f16 l0 = (f16)(ex - (float)h0), l1 = (f16)(ey - (float)h1);
    f16 l2 = (f16)(ez - (float)h2), l3 = (f16)(ew - (float)h3);
    f16x4 hi = {h0, h1, h2, h3}, lo = {l0, l1, l2, l3};
    int kt  = c >> 5;
    int sub = ((c & 31) >> 3) * 128 + (row & 15) * 8 + (c & 7);
    size_t base = ((size_t)(row >> 4) * 16);
    *(f16x4*)&Bp[(base + kt)     * 512 + sub] = hi;
    *(f16x4*)&Bp[(base + kt + 8) * 512 + sub] = lo;
}

__global__ void cbnorm_k(const float* __restrict__ cb, float* __restrict__ cbnorm) {
    int gtid = blockIdx.x * blockDim.x + threadIdx.x;
    int wave = gtid >> 6;
    int lane = threadIdx.x & 63;
    if (wave >= VCODES) return;
    float4 v = *(const float4*)(cb + (size_t)wave * DDIM + lane * 4);
    float s = v.x * v.x + v.y * v.y + v.z * v.z + v.w * v.w;
    #pragma unroll
    for (int m = 32; m; m >>= 1) s += __shfl_xor(s, m, 64);
    if (lane == 0) cbnorm[wave] = s;
}

// ---------- main: K=768 fp16-split GEMM + in-register argmin ----------
// grid (16384/128, 8192/512); block 256 (4 waves, 2x2).
// Double-buffered LDS (2 x 32 KB), ONE __syncthreads per K-chunk:
//   B_t drains: staging of buf[t&1] (vmcnt) AND prev reads of buf[(t+1)&1]
//   (lgkmcnt) -> stage(t+1) after B_t can never clobber live reads, and
//   reads of buf[t&1] after B_t always see completed staging. Race-free.
__global__ __launch_bounds__(256, 2)
void vq_mfma(const f16* __restrict__ Ap, const f16* __restrict__ Bp,
             const float* __restrict__ cbn,
             float* __restrict__ pmin, int* __restrict__ pidx) {
    __shared__ __align__(16) f16 As[2][16 * 512];   // [buf][8 subtiles][2 halves][512]
    __shared__ __align__(16) f16 Bs[2][16 * 512];

    const int tid  = threadIdx.x;
    const int lane = tid & 63;
    const int w    = tid >> 6;
    const int wr   = w >> 1, wc = w & 1;
    const int l15  = lane & 15;
    const int l4   = lane >> 4;
    const int r0   = blockIdx.x * 128;
    const int vgrp = blockIdx.y;

    const char* Ag = (const char*)Ap + (size_t)(r0 >> 4) * 16384;
    const char* Bp0 = (const char*)Bp;

    // stage chunk (vt_, vc_) into buffer b. 4 A-loads then 4 B-loads per thread.
    auto stage = [&](int vt_, int vc_, int b) {
        const int akt = (vc_ < 8) ? (vc_ & 3) * 2 : 8 + (vc_ - 8) * 2;
        const int bkt = (vc_ < 4) ? vc_ * 2 : (vc_ < 8) ? 8 + (vc_ - 4) * 2 : (vc_ - 8) * 2;
        const char* Bg = Bp0 + (size_t)((vgrp * 512 + vt_ * 128) >> 4) * 16384;
        #pragma unroll
        for (int i = 0; i < 4; i++) {
            const int off = i * 4096 + tid * 16;
            const int s   = off >> 11;
            const int h   = (off >> 10) & 1;
            const int win = off & 1023;
            gload16(Ag + ((size_t)s * 16 + (akt + h)) * 1024 + win, (char*)As[b] + off);
        }
        #pragma unroll
        for (int i = 0; i < 4; i++) {
            const int off = i * 4096 + tid * 16;
            const int s   = off >> 11;
            const int h   = (off >> 10) & 1;
            const int win = off & 1023;
            gload16(Bg + ((size_t)s * 16 + (bkt + h)) * 1024 + win, (char*)Bs[b] + off);
        }
    };

    float rmin[4][4];
    int   ridx[4][4];
    #pragma unroll
    for (int m = 0; m < 4; m++)
        #pragma unroll
        for (int r = 0; r < 4; r++) { rmin[m][r] = 3.4e38f; ridx[m][r] = 0x7fffffff; }

    stage(0, 0, 0);   // prologue

    for (int vt = 0; vt < 4; vt++) {
        const int v0 = vgrp * 512 + vt * 128;

        f32x4 acc[4][4];
        #pragma unroll
        for (int m = 0; m < 4; m++)
            #pragma unroll
            for (int n = 0; n < 4; n++) acc[m][n] = (f32x4){0.f, 0.f, 0.f, 0.f};

        for (int vc = 0; vc < 12; vc++) {
            const int cc = vt * 12 + vc;
            const int b  = cc & 1;
            __syncthreads();
            if (cc < 47) {
                const int nvt = (vc == 11) ? vt + 1 : vt;
                const int nvc = (vc == 11) ? 0 : vc + 1;
                stage(nvt, nvc, (cc + 1) & 1);
            }
            #pragma unroll
            for (int h = 0; h < 2; h++) {
                f16x8 af[4], bf[4];
                #pragma unroll
                for (int m = 0; m < 4; m++)
                    af[m] = *(const f16x8*)(As[b] + ((wr * 4 + m) * 2 + h) * 512 + lane * 8);
                #pragma unroll
                for (int n = 0; n < 4; n++)
                    bf[n] = *(const f16x8*)(Bs[b] + ((wc * 4 + n) * 2 + h) * 512 + lane * 8);
                #pragma unroll
                for (int m = 0; m < 4; m++)
                    #pragma unroll
                    for (int n = 0; n < 4; n++)
                        acc[m][n] = __builtin_amdgcn_mfma_f32_16x16x32_f16(af[m], bf[n], acc[m][n], 0, 0, 0);
            }
        }

        // score = ||e||^2 - 2 x.e = cn - acc/32  (acc = 64 * x.e)
        #pragma unroll
        for (int n = 0; n < 4; n++) {
            const int c = v0 + wc * 64 + n * 16 + l15;
            const float cn = cbn[c];
            #pragma unroll
            for (int m = 0; m < 4; m++)
                #pragma unroll
                for (int r = 0; r < 4; r++) {
                    float s = cn - acc[m][n][r] * 0.03125f;
                    if (s < rmin[m][r] || (s == rmin[m][r] && c < ridx[m][r])) {
                        rmin[m][r] = s; ridx[m][r] = c;
                    }
                }
        }
    }

    #pragma unroll
    for (int m = 0; m < 4; m++)
        #pragma unroll
        for (int r = 0; r < 4; r++) {
            float mv = rmin[m][r];
            int   id = ridx[m][r];
            #pragma unroll
            for (int o = 1; o < 16; o <<= 1) {
                float om = __shfl_xor(mv, o, 64);
                int  oid = __shfl_xor(id, o, 64);
                if (om < mv || (om == mv && oid < id)) { mv = om; id = oid; }
            }
            if (l15 == 0) {
                const int grow = r0 + wr * 64 + m * 16 + l4 * 4 + r;
                pmin[grow * 32 + vgrp * 2 + wc] = mv;
                pidx[grow * 32 + vgrp * 2 + wc] = id;
            }
        }
}

// ---------- combine partials + gather + partial loss ----------
__global__ void combine_k(const float* __restrict__ lat, const float* __restrict__ cb,
                          const float* __restrict__ pmin, const int* __restrict__ pidx,
                          float* __restrict__ out_q, float* __restrict__ out_idx,
                          float* __restrict__ loss_part) {
    const int tid = threadIdx.x, lane = tid & 63, wv = tid >> 6;
    const int row = blockIdx.x * 4 + wv;

    float m = 3.4e38f; int id = 0x7fffffff;
    if (lane < 32) { m = pmin[row * 32 + lane]; id = pidx[row * 32 + lane]; }
    #pragma unroll
    for (int o = 32; o; o >>= 1) {
        float om = __shfl_xor(m, o, 64);
        int  oid = __shfl_xor(id, o, 64);
        if (om < m || (om == m && oid < id)) { m = om; id = oid; }
    }

    float4 q = *(const float4*)&cb[(size_t)id * DDIM + lane * 4];
    float4 x = *(const float4*)&lat[(size_t)row * DDIM + lane * 4];
    *(float4*)&out_q[(size_t)row * DDIM + lane * 4] = q;
    if (lane == 0) out_idx[row] = (float)id;

    float dx = q.x - x.x, dy = q.y - x.y, dz = q.z - x.z, dw = q.w - x.w;
    float s = dx * dx + dy * dy + dz * dz + dw * dw;
    #pragma unroll
    for (int o = 32; o; o >>= 1) s += __shfl_xor(s, o, 64);

    __shared__ float red[4];
    if (lane == 0) red[wv] = s;
    __syncthreads();
    if (tid == 0) loss_part[blockIdx.x] = red[0] + red[1] + red[2] + red[3];
}

__global__ void loss_k(const float* __restrict__ part, float* __restrict__ out_loss) {
    float s = 0.0f;
    for (int i = threadIdx.x; i < N_ROWS / 4; i += 256) s += part[i];
    #pragma unroll
    for (int m = 32; m; m >>= 1) s += __shfl_xor(s, m, 64);
    __shared__ float wsum[4];
    int lane = threadIdx.x & 63, w = threadIdx.x >> 6;
    if (lane == 0) wsum[w] = s;
    __syncthreads();
    if (threadIdx.x == 0) {
        float t = wsum[0] + wsum[1] + wsum[2] + wsum[3];
        *out_loss = (1.0f + BETA) * t / (float)((size_t)N_ROWS * DDIM);
    }
}

extern "C" void kernel_launch(void* const* d_in, const int* in_sizes, int n_in,
                              void* d_out, int out_size, void* d_ws, size_t ws_size,
                              hipStream_t stream) {
    const float* lat = (const float*)d_in[0];   // [16,32,32,256] fp32
    const float* cb  = (const float*)d_in[1];   // [8192,256] fp32

    float* ws = (float*)d_ws;
    f16*   Ap       = (f16*)ws;                          // 16384*512 f16
    f16*   Bp       = (f16*)(ws + 4194304);              // 8192*512 f16
    float* cbn      = ws + 4194304 + 2097152;            // 8192
    float* pmin     = cbn + VCODES;                      // 16384*32
    int*   pidx     = (int*)(pmin + N_ROWS * 32);        // 16384*32
    float* losspart = (float*)(pidx + N_ROWS * 32);      // 4096

    float* out_q    = (float*)d_out;                     // 4194304
    float* out_loss = out_q + (size_t)N_ROWS * DDIM;     // 1
    float* out_idx  = out_loss + 1;                      // 16384 (as fp32)

    split_lat<<<N_ROWS * DDIM / 1024, 256, 0, stream>>>(lat, Ap);
    split_cb<<<VCODES * DDIM / 1024, 256, 0, stream>>>(cb, Bp);
    cbnorm_k<<<VCODES / 4, 256, 0, stream>>>(cb, cbn);

    dim3 grid(N_ROWS / 128, VCODES / 512);
    vq_mfma<<<grid, 256, 0, stream>>>(Ap, Bp, cbn, pmin, pidx);

    combine_k<<<N_ROWS / 4, 256, 0, stream>>>(lat, cb, pmin, pidx,
                                              out_q, out_idx, losspart);
    loss_k<<<1, 256, 0, stream>>>(losspart, out_loss);
}